// Round 5
// baseline (8899.474 us; speedup 1.0000x reference)
//
#include <hip/hip_runtime.h>
#include <stdint.h>

// SSMTrack: B=8, S=4096, H=1024, D=256
//   inp = x @ W_in + b_in                    (tiled bf16 MFMA GEMM)
//   s_t = tanh(inp_t + s_{t-1} @ W_state + b_state)   (MFMA f16 scan)
//   out = states @ W_out + b_out             (streamed INSIDE the scan kernel)

typedef float v4f __attribute__((ext_vector_type(4)));
typedef __bf16 bf16x4 __attribute__((ext_vector_type(4)));
typedef __bf16 bf16x8 __attribute__((ext_vector_type(8)));
typedef _Float16 h8 __attribute__((ext_vector_type(8)));

#define BARRIER_LGKM() asm volatile("s_waitcnt lgkmcnt(0)\n\ts_barrier" ::: "memory")

#define GLOAD_LDS16(g, l)                                                    \
  __builtin_amdgcn_global_load_lds(                                          \
      (const __attribute__((address_space(1))) void*)(g),                    \
      (__attribute__((address_space(3))) void*)(l), 16, 0, 0)

// ---------------------------------------------------------------- conversions
__global__ void cvt_f32_bf16_x4(const float* __restrict__ in,
                                __bf16* __restrict__ out, int n4) {
  int i = blockIdx.x * blockDim.x + threadIdx.x;
  if (i >= n4) return;
  v4f v = ((const v4f*)in)[i];
  bf16x4 o;
  o.x = (__bf16)v.x; o.y = (__bf16)v.y; o.z = (__bf16)v.z; o.w = (__bf16)v.w;
  ((bf16x4*)out)[i] = o;
}

// in: [K,N] f32 row-major  ->  out: [N,K] bf16 row-major (i.e. B^T)
__global__ void transpose_cvt(const float* __restrict__ in,
                              __bf16* __restrict__ out, int K, int N) {
  int i = blockIdx.x * blockDim.x + threadIdx.x;
  if (i >= K * N) return;
  int k = i / N;
  int n = i - k * N;
  out[(size_t)n * K + k] = (__bf16)in[i];
}

// ---------------------------------------------------------------- GEMM (bf16)
// C[M,N](f32) = A[M,K](bf16 rm) * B + bias, with Bt[N,K] = B^T (bf16 rm).
// 128x128 block tile, BK=32, 4 waves (2x2), 4x4 fragments of 16x16x32 MFMA.
// Double-buffered LDS via global_load_lds (16B), one barrier per K-step.
// Swizzle: 16B-slot s -> s ^ ((row>>1)&3) applied on the global source side
// (m173); ds_read applies the same XOR -> 2-way bank aliasing = free.
__global__ __launch_bounds__(256) void gemm_tile(
    const __bf16* __restrict__ A,    // [M,K]
    const __bf16* __restrict__ Bt,   // [N,K]
    const float* __restrict__ bias,  // [N]
    float* __restrict__ C,           // [M,N]
    int M, int N, int K) {
  const int tid = threadIdx.x;
  const int lane = tid & 63;
  const int w = tid >> 6;          // wave 0..3
  const int wr = w >> 1, wc = w & 1;
  const int r = lane & 15, q = lane >> 4;

  const int nbn = N >> 7;
  const int mb = blockIdx.x / nbn;
  const int nb = blockIdx.x - mb * nbn;
  const int m0 = mb << 7, n0 = nb << 7;

  __shared__ __align__(16) char lds[2][16384];  // [buf][A 8K | B 8K]

  const __bf16* gA[2];
  const __bf16* gB[2];
  int loff[2];
#pragma unroll
  for (int j = 0; j < 2; ++j) {
    int o = (w * 2 + j) * 1024 + lane * 16;
    int row = o >> 6;
    int s = (o >> 4) & 3;
    int ss = s ^ ((row >> 1) & 3);
    gA[j] = A + (size_t)(m0 + row) * K + ss * 8;
    gB[j] = Bt + (size_t)(n0 + row) * K + ss * 8;
    loff[j] = (w * 2 + j) * 1024;
  }

  const int slot = (q ^ ((r >> 1) & 3)) * 16;
  int aoff[4], boff[4];
#pragma unroll
  for (int i = 0; i < 4; ++i) {
    aoff[i] = (wr * 64 + i * 16 + r) * 64 + slot;
    boff[i] = 8192 + (wc * 64 + i * 16 + r) * 64 + slot;
  }

  v4f acc[4][4];
#pragma unroll
  for (int mi = 0; mi < 4; ++mi)
#pragma unroll
    for (int ni = 0; ni < 4; ++ni) acc[mi][ni] = (v4f){0.f, 0.f, 0.f, 0.f};

  const int NK = K >> 5;
#pragma unroll
  for (int j = 0; j < 2; ++j) {
    GLOAD_LDS16(gA[j], lds[0] + loff[j]);
    GLOAD_LDS16(gB[j], lds[0] + 8192 + loff[j]);
  }

  for (int kt = 0; kt < NK; ++kt) {
    __syncthreads();
    if (kt + 1 < NK) {
      const int bb = (kt + 1) & 1;
      const int ke = (kt + 1) * 32;
#pragma unroll
      for (int j = 0; j < 2; ++j) {
        GLOAD_LDS16(gA[j] + ke, lds[bb] + loff[j]);
        GLOAD_LDS16(gB[j] + ke, lds[bb] + 8192 + loff[j]);
      }
    }
    const char* Lb = lds[kt & 1];
    bf16x8 af[4], bf[4];
#pragma unroll
    for (int i = 0; i < 4; ++i) af[i] = *(const bf16x8*)(Lb + aoff[i]);
#pragma unroll
    for (int i = 0; i < 4; ++i) bf[i] = *(const bf16x8*)(Lb + boff[i]);
#pragma unroll
    for (int mi = 0; mi < 4; ++mi)
#pragma unroll
      for (int ni = 0; ni < 4; ++ni)
        acc[mi][ni] = __builtin_amdgcn_mfma_f32_16x16x32_bf16(
            af[mi], bf[ni], acc[mi][ni], 0, 0, 0);
  }

  float bv[4];
#pragma unroll
  for (int ni = 0; ni < 4; ++ni) bv[ni] = bias[n0 + wc * 64 + ni * 16 + r];
#pragma unroll
  for (int mi = 0; mi < 4; ++mi) {
    int rowb = m0 + wr * 64 + mi * 16 + q * 4;
#pragma unroll
    for (int ni = 0; ni < 4; ++ni) {
      int col = n0 + wc * 64 + ni * 16 + r;
      float* cp = C + (size_t)rowb * N + col;
#pragma unroll
      for (int i = 0; i < 4; ++i) cp[(size_t)i * N] = acc[mi][ni][i] + bv[ni];
    }
  }
}

// ---------------------------------------------------------------- fused scan + out-GEMM
// One block of 768 threads per batch.
//  Waves 0..7  : R3 scan (2 waves/SIMD). MFMA 16x16x32_f16, all 16 A-rows
//                aliased to the state vector (broadcast LDS read); wave w owns
//                cols 32w..32w+31 (2 n-tiles, W_state B-frags in regs).
//  Waves 8..11 : gemm3 streamers. out[t] = states[t] @ W_out + b_out depends
//                only on rows already produced, so these waves consume the
//                scan's ~450 bubble cy/step of idle MFMA pipe. They are
//                BARRIER-LOCKED with the scan (same s_barrier count per
//                wave -> no divergent-barrier hang, no spinning): at loop
//                iteration t wave g processes output tile T = 4*(t-LAG)+g
//                (LAG=64 steps: rows needed <= t-49, and by then the scan's
//                fire-and-forget stores have long retired; same block ->
//                same XCD L2 -> coherent). One 16x16 tile/step = 8 MFMAs +
//                16 L2-hot b128 loads, elapsed ~500cy << step. Leftover
//                LAG*4 = 256 tiles drain barrier-free after the loop.
//  s_setprio(1) wraps the scan's MFMA chains: with genuine role diversity
//  (T5 prerequisite) scan MFMAs win pipe arbitration over streamer MFMAs.
__global__ __launch_bounds__(768, 1) void scan_fused(
    const float* __restrict__ inp,      // [B*S, 256] f32
    const float* __restrict__ Wst,      // [256, 256] f32
    const float* __restrict__ b_state,  // [256] f32
    const __bf16* __restrict__ WoutT,   // [1024, 256] bf16 (W_out^T)
    const float* __restrict__ b_out,    // [1024] f32
    __bf16* __restrict__ states,        // [B*S, 256] bf16 (out)
    float* __restrict__ out,            // [B*S, 1024] f32 (final out)
    int S) {
  const int tid = threadIdx.x;
  const int l = tid & 63;
  const int q = l >> 4;
  const int r = l & 15;
  const int w = tid >> 6;             // wave 0..11
  const int b = blockIdx.x;
  const int LAG = 64;

  __shared__ __align__(16) _Float16 sbuf[2][256];

  const float* inpb = inp + (size_t)b * S * 256;
  __bf16* stb = states + (size_t)b * S * 256;

  if (w < 8) {
    // ------------------------------------------------------------ scan role
    h8 bwA[8], bwB[8];
#pragma unroll
    for (int c = 0; c < 8; ++c) {
#pragma unroll
      for (int i = 0; i < 8; ++i) {
        const float* wp = Wst + (size_t)(32 * c + 8 * q + i) * 256 + 32 * w + r;
        bwA[c][i] = (_Float16)wp[0];
        bwB[c][i] = (_Float16)wp[16];
      }
    }

    const int col = 32 * w + 16 * (q & 1) + r;  // this lane's output column
    const float bst = b_state[col];

    if (tid < 256) sbuf[0][tid] = (_Float16)0.f;  // state0 = 0
    float u_cur = inpb[col];          // u for t=0
    float u_nxt = inpb[256 + col];    // u for t=1
    __syncthreads();

    int cur = 0;
    for (int t = 0; t < S; ++t) {
      float u_n2 = 0.f;
      if (t + 2 < S) u_n2 = inpb[(size_t)(t + 2) * 256 + col];

      // A-frags: addr = 64c + 16q -> 4 distinct addrs, broadcast read.
      const h8* sp = (const h8*)sbuf[cur];
      h8 af[8];
#pragma unroll
      for (int c = 0; c < 8; ++c) af[c] = sp[4 * c + q];

      __builtin_amdgcn_s_setprio(1);
      v4f a0 = {0.f, 0.f, 0.f, 0.f};
      v4f a1 = a0;
#pragma unroll
      for (int c = 0; c < 8; ++c) {
        a0 = __builtin_amdgcn_mfma_f32_16x16x32_f16(af[c], bwA[c], a0, 0, 0, 0);
        a1 = __builtin_amdgcn_mfma_f32_16x16x32_f16(af[c], bwB[c], a1, 0, 0, 0);
      }
      __builtin_amdgcn_s_setprio(0);

      float x = ((q & 1) ? a1[0] : a0[0]) + u_cur + bst;

      // tanh(x) = 1 - 2/(exp2(2*log2e*x)+1)
      float e = exp2f(2.885390082f * x);
      float sn = 1.f - 2.f * __builtin_amdgcn_rcpf(e + 1.f);

      cur ^= 1;
      if (q < 2) {
        sbuf[cur][col] = (_Float16)sn;            // ds_write_b16
        stb[(size_t)t * 256 + col] = (__bf16)sn;  // fire-and-forget store
      }
      u_cur = u_nxt;
      u_nxt = u_n2;
      BARRIER_LGKM();
    }
  } else {
    // ------------------------------------------------------------ gemm3 role
    const int g = w - 8;  // 0..3
    auto do_tile = [&](int T) {
      const int m = T >> 6;      // 16-timestep chunk
      const int n = T & 63;      // 16-col chunk of H=1024
      const __bf16* arow = stb + (size_t)(16 * m + r) * 256 + q * 8;
      const __bf16* brow = WoutT + (size_t)(16 * n + r) * 256 + q * 8;
      v4f acc = {0.f, 0.f, 0.f, 0.f};
#pragma unroll
      for (int c = 0; c < 8; ++c) {
        bf16x8 af = *(const bf16x8*)(arow + 32 * c);
        bf16x8 bf = *(const bf16x8*)(brow + 32 * c);
        acc = __builtin_amdgcn_mfma_f32_16x16x32_bf16(af, bf, acc, 0, 0, 0);
      }
      const float bo = b_out[16 * n + r];
      size_t base = ((size_t)b * S + 16 * m + 4 * q) * 1024 + 16 * n + r;
#pragma unroll
      for (int i = 0; i < 4; ++i) out[base + (size_t)i * 1024] = acc[i] + bo;
    };

    __syncthreads();
    for (int t = 0; t < S; ++t) {
      if (t >= LAG) do_tile(4 * (t - LAG) + g);
      BARRIER_LGKM();
    }
    // drain: remaining LAG tile-groups, barrier-free (scan waves have exited)
    for (int k = S - LAG; k < 4096; ++k) do_tile(4 * k + g);
  }
}

// ---------------------------------------------------------------- launch
extern "C" void kernel_launch(void* const* d_in, const int* in_sizes, int n_in,
                              void* d_out, int out_size, void* d_ws,
                              size_t ws_size, hipStream_t stream) {
  const float* x       = (const float*)d_in[0];  // [8,4096,1024]
  const float* W_in    = (const float*)d_in[1];  // [1024,256]
  const float* b_in    = (const float*)d_in[2];  // [256]
  const float* W_state = (const float*)d_in[3];  // [256,256]
  const float* b_state = (const float*)d_in[4];  // [256]
  const float* W_out   = (const float*)d_in[5];  // [256,1024]
  const float* b_out   = (const float*)d_in[6];  // [1024]
  float* out = (float*)d_out;                    // [8,4096,1024]

  const int B = 8, S = 4096, H = 1024, D = 256;
  const int M = B * S;  // 32768

  char* ws = (char*)d_ws;
  float*  inp    = (float*)(ws + 0);            // 32 MB  [M,D] f32
  __bf16* states = (__bf16*)(ws + 33554432);    // 16 MB  [M,D] bf16
  __bf16* xb     = (__bf16*)(ws + 50331648);    // 64 MB  [M,H] bf16
  __bf16* WinT   = (__bf16*)(ws + 117440512);   // 0.5 MB [D,H] bf16  (W_in^T)
  __bf16* WoutT  = (__bf16*)(ws + 117964800);   // 0.5 MB [H,D] bf16  (W_out^T)

  // conversions
  cvt_f32_bf16_x4<<<(M * H / 4 + 255) / 256, 256, 0, stream>>>(x, xb, M * H / 4);
  transpose_cvt<<<(H * D + 255) / 256, 256, 0, stream>>>(W_in, WinT, H, D);
  transpose_cvt<<<(D * H + 255) / 256, 256, 0, stream>>>(W_out, WoutT, D, H);

  // phase 1: inp = x @ W_in + b_in   (M=32768, N=256, K=1024) -> 512 blocks
  gemm_tile<<<(M / 128) * (D / 128), 256, 0, stream>>>(xb, WinT, b_in, inp, M, D, H);

  // phase 2+3 fused: scan + streamed out-GEMM, one 768-thread block per batch
  scan_fused<<<B, 768, 0, stream>>>(inp, W_state, b_state, WoutT, b_out,
                                    states, out, S);
}

// Round 6
// 7823.600 us; speedup vs baseline: 1.1375x; 1.1375x over previous
//
#include <hip/hip_runtime.h>
#include <stdint.h>

// SSMTrack: B=8, S=4096, H=1024, D=256
//   inp = x @ W_in + b_in                    (tiled bf16 MFMA GEMM)
//   s_t = tanh(inp_t + s_{t-1} @ W_state + b_state)   (MFMA f16 scan)
//   out = states @ W_out + b_out             (pipelined streamer waves inside scan kernel)

typedef float v4f __attribute__((ext_vector_type(4)));
typedef __bf16 bf16x4 __attribute__((ext_vector_type(4)));
typedef __bf16 bf16x8 __attribute__((ext_vector_type(8)));
typedef _Float16 h8 __attribute__((ext_vector_type(8)));

#define BARRIER_LGKM() asm volatile("s_waitcnt lgkmcnt(0)\n\ts_barrier" ::: "memory")

#define GLOAD_LDS16(g, l)                                                    \
  __builtin_amdgcn_global_load_lds(                                          \
      (const __attribute__((address_space(1))) void*)(g),                    \
      (__attribute__((address_space(3))) void*)(l), 16, 0, 0)

// ---------------------------------------------------------------- conversions
__global__ void cvt_f32_bf16_x4(const float* __restrict__ in,
                                __bf16* __restrict__ out, int n4) {
  int i = blockIdx.x * blockDim.x + threadIdx.x;
  if (i >= n4) return;
  v4f v = ((const v4f*)in)[i];
  bf16x4 o;
  o.x = (__bf16)v.x; o.y = (__bf16)v.y; o.z = (__bf16)v.z; o.w = (__bf16)v.w;
  ((bf16x4*)out)[i] = o;
}

// in: [K,N] f32 row-major  ->  out: [N,K] bf16 row-major (i.e. B^T)
__global__ void transpose_cvt(const float* __restrict__ in,
                              __bf16* __restrict__ out, int K, int N) {
  int i = blockIdx.x * blockDim.x + threadIdx.x;
  if (i >= K * N) return;
  int k = i / N;
  int n = i - k * N;
  out[(size_t)n * K + k] = (__bf16)in[i];
}

// ---------------------------------------------------------------- GEMM (bf16)
// C[M,N](f32) = A[M,K](bf16 rm) * B + bias, with Bt[N,K] = B^T (bf16 rm).
// 128x128 block tile, BK=32, 4 waves (2x2), 4x4 fragments of 16x16x32 MFMA.
// Double-buffered LDS via global_load_lds (16B), one barrier per K-step.
__global__ __launch_bounds__(256) void gemm_tile(
    const __bf16* __restrict__ A,    // [M,K]
    const __bf16* __restrict__ Bt,   // [N,K]
    const float* __restrict__ bias,  // [N]
    float* __restrict__ C,           // [M,N]
    int M, int N, int K) {
  const int tid = threadIdx.x;
  const int lane = tid & 63;
  const int w = tid >> 6;          // wave 0..3
  const int wr = w >> 1, wc = w & 1;
  const int r = lane & 15, q = lane >> 4;

  const int nbn = N >> 7;
  const int mb = blockIdx.x / nbn;
  const int nb = blockIdx.x - mb * nbn;
  const int m0 = mb << 7, n0 = nb << 7;

  __shared__ __align__(16) char lds[2][16384];  // [buf][A 8K | B 8K]

  const __bf16* gA[2];
  const __bf16* gB[2];
  int loff[2];
#pragma unroll
  for (int j = 0; j < 2; ++j) {
    int o = (w * 2 + j) * 1024 + lane * 16;
    int row = o >> 6;
    int s = (o >> 4) & 3;
    int ss = s ^ ((row >> 1) & 3);
    gA[j] = A + (size_t)(m0 + row) * K + ss * 8;
    gB[j] = Bt + (size_t)(n0 + row) * K + ss * 8;
    loff[j] = (w * 2 + j) * 1024;
  }

  const int slot = (q ^ ((r >> 1) & 3)) * 16;
  int aoff[4], boff[4];
#pragma unroll
  for (int i = 0; i < 4; ++i) {
    aoff[i] = (wr * 64 + i * 16 + r) * 64 + slot;
    boff[i] = 8192 + (wc * 64 + i * 16 + r) * 64 + slot;
  }

  v4f acc[4][4];
#pragma unroll
  for (int mi = 0; mi < 4; ++mi)
#pragma unroll
    for (int ni = 0; ni < 4; ++ni) acc[mi][ni] = (v4f){0.f, 0.f, 0.f, 0.f};

  const int NK = K >> 5;
#pragma unroll
  for (int j = 0; j < 2; ++j) {
    GLOAD_LDS16(gA[j], lds[0] + loff[j]);
    GLOAD_LDS16(gB[j], lds[0] + 8192 + loff[j]);
  }

  for (int kt = 0; kt < NK; ++kt) {
    __syncthreads();
    if (kt + 1 < NK) {
      const int bb = (kt + 1) & 1;
      const int ke = (kt + 1) * 32;
#pragma unroll
      for (int j = 0; j < 2; ++j) {
        GLOAD_LDS16(gA[j] + ke, lds[bb] + loff[j]);
        GLOAD_LDS16(gB[j] + ke, lds[bb] + 8192 + loff[j]);
      }
    }
    const char* Lb = lds[kt & 1];
    bf16x8 af[4], bf[4];
#pragma unroll
    for (int i = 0; i < 4; ++i) af[i] = *(const bf16x8*)(Lb + aoff[i]);
#pragma unroll
    for (int i = 0; i < 4; ++i) bf[i] = *(const bf16x8*)(Lb + boff[i]);
#pragma unroll
    for (int mi = 0; mi < 4; ++mi)
#pragma unroll
      for (int ni = 0; ni < 4; ++ni)
        acc[mi][ni] = __builtin_amdgcn_mfma_f32_16x16x32_bf16(
            af[mi], bf[ni], acc[mi][ni], 0, 0, 0);
  }

  float bv[4];
#pragma unroll
  for (int ni = 0; ni < 4; ++ni) bv[ni] = bias[n0 + wc * 64 + ni * 16 + r];
#pragma unroll
  for (int mi = 0; mi < 4; ++mi) {
    int rowb = m0 + wr * 64 + mi * 16 + q * 4;
#pragma unroll
    for (int ni = 0; ni < 4; ++ni) {
      int col = n0 + wc * 64 + ni * 16 + r;
      float* cp = C + (size_t)rowb * N + col;
#pragma unroll
      for (int i = 0; i < 4; ++i) cp[(size_t)i * N] = acc[mi][ni][i] + bv[ni];
    }
  }
}

// ---------------------------------------------------------------- fused scan + out-GEMM
// One block of 768 threads per batch.
//  Waves 0..7  : R4 scan (2 waves/SIMD), unchanged.
//  Waves 8..11 : PIPELINED gemm3 streamers. R5's failure: streamers consumed
//    their 16 global loads immediately -> per-step serial latency chain
//    ~2-4K cy dragged every barrier (step 1066 -> 5073 cy). Fix: double-
//    buffered register tiles (E/O, loop unrolled x2 for static reg indexing)
//    -- issue tile k+2's loads in step t, consume tile k's already-landed
//    registers. Barrier-to-barrier streamer path = 8 MFMA (2 chains depth 4)
//    + 4 stores ~300 cy << scan's ~1066 cy path; loads get a full step to
//    land. Tile map, LAG=64, and store addressing byte-identical to R5
//    (correctness-proven there). Barrier counts: both roles hit S+1.
__global__ __launch_bounds__(768, 1) void scan_fused(
    const float* __restrict__ inp,      // [B*S, 256] f32
    const float* __restrict__ Wst,      // [256, 256] f32
    const float* __restrict__ b_state,  // [256] f32
    const __bf16* __restrict__ WoutT,   // [1024, 256] bf16 (W_out^T)
    const float* __restrict__ b_out,    // [1024] f32
    __bf16* __restrict__ states,        // [B*S, 256] bf16 (out)
    float* __restrict__ out,            // [B*S, 1024] f32 (final out)
    int S) {
  const int tid = threadIdx.x;
  const int l = tid & 63;
  const int q = l >> 4;
  const int r = l & 15;
  const int w = tid >> 6;             // wave 0..11
  const int b = blockIdx.x;
  const int LAG = 64;

  __shared__ __align__(16) _Float16 sbuf[2][256];

  const float* inpb = inp + (size_t)b * S * 256;
  __bf16* stb = states + (size_t)b * S * 256;

  if (w < 8) {
    // ------------------------------------------------------------ scan role
    h8 bwA[8], bwB[8];
#pragma unroll
    for (int c = 0; c < 8; ++c) {
#pragma unroll
      for (int i = 0; i < 8; ++i) {
        const float* wp = Wst + (size_t)(32 * c + 8 * q + i) * 256 + 32 * w + r;
        bwA[c][i] = (_Float16)wp[0];
        bwB[c][i] = (_Float16)wp[16];
      }
    }

    const int col = 32 * w + 16 * (q & 1) + r;  // this lane's output column
    const float bst = b_state[col];

    if (tid < 256) sbuf[0][tid] = (_Float16)0.f;  // state0 = 0
    float u_cur = inpb[col];          // u for t=0
    float u_nxt = inpb[256 + col];    // u for t=1
    __syncthreads();

    int cur = 0;
    for (int t = 0; t < S; ++t) {
      float u_n2 = 0.f;
      if (t + 2 < S) u_n2 = inpb[(size_t)(t + 2) * 256 + col];

      // A-frags: addr = 64c + 16q -> 4 distinct addrs, broadcast read.
      const h8* sp = (const h8*)sbuf[cur];
      h8 af[8];
#pragma unroll
      for (int c = 0; c < 8; ++c) af[c] = sp[4 * c + q];

      __builtin_amdgcn_s_setprio(1);
      v4f a0 = {0.f, 0.f, 0.f, 0.f};
      v4f a1 = a0;
#pragma unroll
      for (int c = 0; c < 8; ++c) {
        a0 = __builtin_amdgcn_mfma_f32_16x16x32_f16(af[c], bwA[c], a0, 0, 0, 0);
        a1 = __builtin_amdgcn_mfma_f32_16x16x32_f16(af[c], bwB[c], a1, 0, 0, 0);
      }
      __builtin_amdgcn_s_setprio(0);

      float x = ((q & 1) ? a1[0] : a0[0]) + u_cur + bst;

      // tanh(x) = 1 - 2/(exp2(2*log2e*x)+1)
      float e = exp2f(2.885390082f * x);
      float sn = 1.f - 2.f * __builtin_amdgcn_rcpf(e + 1.f);

      cur ^= 1;
      if (q < 2) {
        sbuf[cur][col] = (_Float16)sn;            // ds_write_b16
        stb[(size_t)t * 256 + col] = (__bf16)sn;  // fire-and-forget store
      }
      u_cur = u_nxt;
      u_nxt = u_n2;
      BARRIER_LGKM();
    }
  } else {
    // ------------------------------------------------------------ gemm3 role
    const int g = w - 8;  // 0..3
    const int NT = S;     // tiles per streamer wave (4*S total / 4 waves)

    // issue: fire tile 4k+g's 17 loads into the given register set (no wait)
    auto issue = [&](int k, bf16x8 (&AF)[8], bf16x8 (&BF)[8], float& BO) {
      const int T = 4 * k + g;
      const int m = T >> 6, n = T & 63;
      const __bf16* ar = stb + (size_t)(16 * m + r) * 256 + q * 8;
      const __bf16* br = WoutT + (size_t)(16 * n + r) * 256 + q * 8;
#pragma unroll
      for (int c = 0; c < 8; ++c) {
        AF[c] = *(const bf16x8*)(ar + 32 * c);
        BF[c] = *(const bf16x8*)(br + 32 * c);
      }
      BO = b_out[16 * n + r];
    };
    // compute: 8 MFMAs (2 chains of depth 4) + stores for tile 4k+g
    auto compute = [&](int k, bf16x8 (&AF)[8], bf16x8 (&BF)[8], float BO) {
      const int T = 4 * k + g;
      const int m = T >> 6, n = T & 63;
      v4f aL = {0.f, 0.f, 0.f, 0.f};
      v4f aH = aL;
#pragma unroll
      for (int c = 0; c < 4; ++c) {
        aL = __builtin_amdgcn_mfma_f32_16x16x32_bf16(AF[c], BF[c], aL, 0, 0, 0);
        aH = __builtin_amdgcn_mfma_f32_16x16x32_bf16(AF[c + 4], BF[c + 4], aH, 0, 0, 0);
      }
      size_t base = ((size_t)b * S + 16 * m + 4 * q) * 1024 + 16 * n + r;
#pragma unroll
      for (int i = 0; i < 4; ++i)
        out[base + (size_t)i * 1024] = aL[i] + aH[i] + BO;
    };

    bf16x8 AE[8], BE[8], AO[8], BOv[8];
    float bE = 0.f, bO = 0.f;

    __syncthreads();                       // matches scan's initial barrier
    for (int t = 0; t < LAG - 2; ++t) BARRIER_LGKM();
    issue(0, AE, BE, bE);
    BARRIER_LGKM();
    issue(1, AO, BOv, bO);
    BARRIER_LGKM();
    // main: t2 = LAG .. S-2 step 2; computes tiles k=0..S-LAG-1;
    // issues k+2, k+3 (always < NT). Barriers: 2 per iteration.
    int k = 0;
    for (int t2 = LAG; t2 < S; t2 += 2) {
      compute(k, AE, BE, bE);
      issue(k + 2, AE, BE, bE);
      BARRIER_LGKM();
      compute(k + 1, AO, BOv, bO);
      issue(k + 3, AO, BOv, bO);
      BARRIER_LGKM();
      k += 2;
    }
    // drain: tiles k = S-LAG .. NT-1 (64), barrier-free (scan waves exited).
    for (; k < NT; k += 2) {
      compute(k, AE, BE, bE);
      if (k + 2 < NT) issue(k + 2, AE, BE, bE);
      compute(k + 1, AO, BOv, bO);
      if (k + 3 < NT) issue(k + 3, AO, BOv, bO);
    }
  }
}

// ---------------------------------------------------------------- launch
extern "C" void kernel_launch(void* const* d_in, const int* in_sizes, int n_in,
                              void* d_out, int out_size, void* d_ws,
                              size_t ws_size, hipStream_t stream) {
  const float* x       = (const float*)d_in[0];  // [8,4096,1024]
  const float* W_in    = (const float*)d_in[1];  // [1024,256]
  const float* b_in    = (const float*)d_in[2];  // [256]
  const float* W_state = (const float*)d_in[3];  // [256,256]
  const float* b_state = (const float*)d_in[4];  // [256]
  const float* W_out   = (const float*)d_in[5];  // [256,1024]
  const float* b_out   = (const float*)d_in[6];  // [1024]
  float* out = (float*)d_out;                    // [8,4096,1024]

  const int B = 8, S = 4096, H = 1024, D = 256;
  const int M = B * S;  // 32768

  char* ws = (char*)d_ws;
  float*  inp    = (float*)(ws + 0);            // 32 MB  [M,D] f32
  __bf16* states = (__bf16*)(ws + 33554432);    // 16 MB  [M,D] bf16
  __bf16* xb     = (__bf16*)(ws + 50331648);    // 64 MB  [M,H] bf16
  __bf16* WinT   = (__bf16*)(ws + 117440512);   // 0.5 MB [D,H] bf16  (W_in^T)
  __bf16* WoutT  = (__bf16*)(ws + 117964800);   // 0.5 MB [H,D] bf16  (W_out^T)

  // conversions
  cvt_f32_bf16_x4<<<(M * H / 4 + 255) / 256, 256, 0, stream>>>(x, xb, M * H / 4);
  transpose_cvt<<<(H * D + 255) / 256, 256, 0, stream>>>(W_in, WinT, H, D);
  transpose_cvt<<<(D * H + 255) / 256, 256, 0, stream>>>(W_out, WoutT, D, H);

  // phase 1: inp = x @ W_in + b_in   (M=32768, N=256, K=1024) -> 512 blocks
  gemm_tile<<<(M / 128) * (D / 128), 256, 0, stream>>>(xb, WinT, b_in, inp, M, D, H);

  // phase 2+3 fused: scan + pipelined out-GEMM streamers, 768 thr/block
  scan_fused<<<B, 768, 0, stream>>>(inp, W_state, b_state, WoutT, b_out,
                                    states, out, S);
}

// Round 7
// 3752.262 us; speedup vs baseline: 2.3718x; 2.0850x over previous
//
#include <hip/hip_runtime.h>
#include <stdint.h>

// SSMTrack: B=8, S=4096, H=1024, D=256
//   inp = x @ W_in + b_in                    (tiled bf16 MFMA GEMM)
//   s_t = tanh(inp_t + s_{t-1} @ W_state + b_state)   (MFMA f16 scan)
//   out = states @ W_out + b_out             (zero-VGPR LDS streamer waves inside scan kernel)

typedef float v4f __attribute__((ext_vector_type(4)));
typedef __bf16 bf16x4 __attribute__((ext_vector_type(4)));
typedef __bf16 bf16x8 __attribute__((ext_vector_type(8)));
typedef _Float16 h8 __attribute__((ext_vector_type(8)));

#define BARRIER_LGKM() asm volatile("s_waitcnt lgkmcnt(0)\n\ts_barrier" ::: "memory")

#define GLOAD_LDS16(g, l)                                                    \
  __builtin_amdgcn_global_load_lds(                                          \
      (const __attribute__((address_space(1))) void*)(g),                    \
      (__attribute__((address_space(3))) void*)(l), 16, 0, 0)

// ---------------------------------------------------------------- conversions
__global__ void cvt_f32_bf16_x4(const float* __restrict__ in,
                                __bf16* __restrict__ out, int n4) {
  int i = blockIdx.x * blockDim.x + threadIdx.x;
  if (i >= n4) return;
  v4f v = ((const v4f*)in)[i];
  bf16x4 o;
  o.x = (__bf16)v.x; o.y = (__bf16)v.y; o.z = (__bf16)v.z; o.w = (__bf16)v.w;
  ((bf16x4*)out)[i] = o;
}

// in: [K,N] f32 row-major  ->  out: [N,K] bf16 row-major (i.e. B^T)
__global__ void transpose_cvt(const float* __restrict__ in,
                              __bf16* __restrict__ out, int K, int N) {
  int i = blockIdx.x * blockDim.x + threadIdx.x;
  if (i >= K * N) return;
  int k = i / N;
  int n = i - k * N;
  out[(size_t)n * K + k] = (__bf16)in[i];
}

// ---------------------------------------------------------------- GEMM (bf16)
// C[M,N](f32) = A[M,K](bf16 rm) * B + bias, with Bt[N,K] = B^T (bf16 rm).
// 128x128 block tile, BK=32, 4 waves (2x2), 4x4 fragments of 16x16x32 MFMA.
// Double-buffered LDS via global_load_lds (16B), one barrier per K-step.
__global__ __launch_bounds__(256) void gemm_tile(
    const __bf16* __restrict__ A,    // [M,K]
    const __bf16* __restrict__ Bt,   // [N,K]
    const float* __restrict__ bias,  // [N]
    float* __restrict__ C,           // [M,N]
    int M, int N, int K) {
  const int tid = threadIdx.x;
  const int lane = tid & 63;
  const int w = tid >> 6;          // wave 0..3
  const int wr = w >> 1, wc = w & 1;
  const int r = lane & 15, q = lane >> 4;

  const int nbn = N >> 7;
  const int mb = blockIdx.x / nbn;
  const int nb = blockIdx.x - mb * nbn;
  const int m0 = mb << 7, n0 = nb << 7;

  __shared__ __align__(16) char lds[2][16384];  // [buf][A 8K | B 8K]

  const __bf16* gA[2];
  const __bf16* gB[2];
  int loff[2];
#pragma unroll
  for (int j = 0; j < 2; ++j) {
    int o = (w * 2 + j) * 1024 + lane * 16;
    int row = o >> 6;
    int s = (o >> 4) & 3;
    int ss = s ^ ((row >> 1) & 3);
    gA[j] = A + (size_t)(m0 + row) * K + ss * 8;
    gB[j] = Bt + (size_t)(n0 + row) * K + ss * 8;
    loff[j] = (w * 2 + j) * 1024;
  }

  const int slot = (q ^ ((r >> 1) & 3)) * 16;
  int aoff[4], boff[4];
#pragma unroll
  for (int i = 0; i < 4; ++i) {
    aoff[i] = (wr * 64 + i * 16 + r) * 64 + slot;
    boff[i] = 8192 + (wc * 64 + i * 16 + r) * 64 + slot;
  }

  v4f acc[4][4];
#pragma unroll
  for (int mi = 0; mi < 4; ++mi)
#pragma unroll
    for (int ni = 0; ni < 4; ++ni) acc[mi][ni] = (v4f){0.f, 0.f, 0.f, 0.f};

  const int NK = K >> 5;
#pragma unroll
  for (int j = 0; j < 2; ++j) {
    GLOAD_LDS16(gA[j], lds[0] + loff[j]);
    GLOAD_LDS16(gB[j], lds[0] + 8192 + loff[j]);
  }

  for (int kt = 0; kt < NK; ++kt) {
    __syncthreads();
    if (kt + 1 < NK) {
      const int bb = (kt + 1) & 1;
      const int ke = (kt + 1) * 32;
#pragma unroll
      for (int j = 0; j < 2; ++j) {
        GLOAD_LDS16(gA[j] + ke, lds[bb] + loff[j]);
        GLOAD_LDS16(gB[j] + ke, lds[bb] + 8192 + loff[j]);
      }
    }
    const char* Lb = lds[kt & 1];
    bf16x8 af[4], bf[4];
#pragma unroll
    for (int i = 0; i < 4; ++i) af[i] = *(const bf16x8*)(Lb + aoff[i]);
#pragma unroll
    for (int i = 0; i < 4; ++i) bf[i] = *(const bf16x8*)(Lb + boff[i]);
#pragma unroll
    for (int mi = 0; mi < 4; ++mi)
#pragma unroll
      for (int ni = 0; ni < 4; ++ni)
        acc[mi][ni] = __builtin_amdgcn_mfma_f32_16x16x32_bf16(
            af[mi], bf[ni], acc[mi][ni], 0, 0, 0);
  }

  float bv[4];
#pragma unroll
  for (int ni = 0; ni < 4; ++ni) bv[ni] = bias[n0 + wc * 64 + ni * 16 + r];
#pragma unroll
  for (int mi = 0; mi < 4; ++mi) {
    int rowb = m0 + wr * 64 + mi * 16 + q * 4;
#pragma unroll
    for (int ni = 0; ni < 4; ++ni) {
      int col = n0 + wc * 64 + ni * 16 + r;
      float* cp = C + (size_t)rowb * N + col;
#pragma unroll
      for (int i = 0; i < 4; ++i) cp[(size_t)i * N] = acc[mi][ni][i] + bv[ni];
    }
  }
}

// ---------------------------------------------------------------- fused scan + out-GEMM
// One block of 768 threads per batch.
//  Waves 0..7  : scan (2 waves/SIMD), byte-identical to R4/R6.
//  Waves 8..11 : ZERO-VGPR streamers. R6 failed on register spill: 128 live
//    VGPRs of double-buffered tiles vs VGPR_Count=80 -> tile arrays went to
//    scratch (~3300 cy/step of private-memory round-trips). Fix:
//      - B-tile (WoutT rows) staged through LDS via global_load_lds: the
//        in-flight data costs NO VGPRs. Double-buffered 2x8KB per wave.
//      - m-major tile map: wave g, tile k -> (m = k>>4, n = 16g + (k&15)),
//        so the A-tile (states rows 16m..16m+15, 32 VGPRs) is reloaded only
//        once per 16 steps.
//      - counted wait: issue next tile's 8 gload_lds + 1 b_out load, then
//        s_waitcnt vmcnt(9) -> previous tile's loads (a full step old) are
//        retired, next tile's stay in flight. Never vmcnt(0) in main loop.
//      - LDS swizzle slot^(row&7) (applied on the global source address,
//        m173 pattern) -> frag ds_read_b128 is 2-way = conflict-free.
//    Barrier-to-barrier streamer path ~500 cy << scan's ~1066 cy.
//    LAG=64 steps: tile k needs states rows <= k+15 = t-49; stores retired.
__global__ __launch_bounds__(768, 1) void scan_fused(
    const float* __restrict__ inp,      // [B*S, 256] f32
    const float* __restrict__ Wst,      // [256, 256] f32
    const float* __restrict__ b_state,  // [256] f32
    const __bf16* __restrict__ WoutT,   // [1024, 256] bf16 (W_out^T)
    const float* __restrict__ b_out,    // [1024] f32
    __bf16* __restrict__ states,        // [B*S, 256] bf16 (out)
    float* __restrict__ out,            // [B*S, 1024] f32 (final out)
    int S) {
  const int tid = threadIdx.x;
  const int l = tid & 63;
  const int q = l >> 4;
  const int r = l & 15;
  const int w = tid >> 6;             // wave 0..11
  const int b = blockIdx.x;
  const int LAG = 64;

  __shared__ __align__(16) _Float16 sbuf[2][256];
  __shared__ __align__(16) char sB[4][2][8192];  // streamer B-tiles

  const float* inpb = inp + (size_t)b * S * 256;
  __bf16* stb = states + (size_t)b * S * 256;

  if (w < 8) {
    // ------------------------------------------------------------ scan role
    h8 bwA[8], bwB[8];
#pragma unroll
    for (int c = 0; c < 8; ++c) {
#pragma unroll
      for (int i = 0; i < 8; ++i) {
        const float* wp = Wst + (size_t)(32 * c + 8 * q + i) * 256 + 32 * w + r;
        bwA[c][i] = (_Float16)wp[0];
        bwB[c][i] = (_Float16)wp[16];
      }
    }

    const int col = 32 * w + 16 * (q & 1) + r;  // this lane's output column
    const float bst = b_state[col];

    if (tid < 256) sbuf[0][tid] = (_Float16)0.f;  // state0 = 0
    float u_cur = inpb[col];          // u for t=0
    float u_nxt = inpb[256 + col];    // u for t=1
    __syncthreads();

    int cur = 0;
    for (int t = 0; t < S; ++t) {
      float u_n2 = 0.f;
      if (t + 2 < S) u_n2 = inpb[(size_t)(t + 2) * 256 + col];

      // A-frags: addr = 64c + 16q -> 4 distinct addrs, broadcast read.
      const h8* sp = (const h8*)sbuf[cur];
      h8 af[8];
#pragma unroll
      for (int c = 0; c < 8; ++c) af[c] = sp[4 * c + q];

      __builtin_amdgcn_s_setprio(1);
      v4f a0 = {0.f, 0.f, 0.f, 0.f};
      v4f a1 = a0;
#pragma unroll
      for (int c = 0; c < 8; ++c) {
        a0 = __builtin_amdgcn_mfma_f32_16x16x32_f16(af[c], bwA[c], a0, 0, 0, 0);
        a1 = __builtin_amdgcn_mfma_f32_16x16x32_f16(af[c], bwB[c], a1, 0, 0, 0);
      }
      __builtin_amdgcn_s_setprio(0);

      float x = ((q & 1) ? a1[0] : a0[0]) + u_cur + bst;

      // tanh(x) = 1 - 2/(exp2(2*log2e*x)+1)
      float e = exp2f(2.885390082f * x);
      float sn = 1.f - 2.f * __builtin_amdgcn_rcpf(e + 1.f);

      cur ^= 1;
      if (q < 2) {
        sbuf[cur][col] = (_Float16)sn;            // ds_write_b16
        stb[(size_t)t * 256 + col] = (__bf16)sn;  // fire-and-forget store
      }
      u_cur = u_nxt;
      u_nxt = u_n2;
      BARRIER_LGKM();
    }
  } else {
    // ------------------------------------------------------------ gemm3 role
    const int g = w - 8;  // 0..3
    char* myB = &sB[g][0][0];
    const int R0 = l >> 5;      // staging: lane covers row 2j+R0, slot Sw
    const int Sw = l & 31;

    bf16x8 Areg[8];
    float boC = 0.f, boN = 0.f;

    // stage B-tile for tile index kn into LDS buf kn&1 (8 gload_lds, 0 VGPRs)
    auto stageB = [&](int kn) {
      const int n = 16 * g + (kn & 15);
      char* dst = myB + (kn & 1) * 8192;
      const __bf16* base = WoutT + (size_t)(16 * n) * 256;
#pragma unroll
      for (int j = 0; j < 8; ++j) {
        const int R = 2 * j + R0;
        const __bf16* src = base + (size_t)R * 256 + ((Sw ^ (R & 7)) << 3);
        GLOAD_LDS16(src, dst + j * 1024);
      }
      boN = b_out[16 * n + r];
    };
    // A-tile (states rows 16m..16m+15) into registers: af[c] = A[r][8q+32c..]
    auto loadA = [&](int m) {
      const __bf16* ar = stb + (size_t)(16 * m + r) * 256 + q * 8;
#pragma unroll
      for (int c = 0; c < 8; ++c) Areg[c] = *(const bf16x8*)(ar + 32 * c);
    };
    // consume tile k from LDS buf k&1: 8 swizzled ds_read_b128 + 8 MFMA
    auto consume = [&](int k) {
      const int n = 16 * g + (k & 15);
      const int m = k >> 4;
      const char* src = myB + (k & 1) * 8192;
      bf16x8 bf[8];
#pragma unroll
      for (int c = 0; c < 8; ++c)
        bf[c] = *(const bf16x8*)(src + r * 512 +
                                 ((((c << 2) + q) ^ (r & 7)) << 4));
      v4f aL = {0.f, 0.f, 0.f, 0.f};
      v4f aH = aL;
#pragma unroll
      for (int c = 0; c < 4; ++c) {
        aL = __builtin_amdgcn_mfma_f32_16x16x32_bf16(Areg[c], bf[c], aL, 0, 0, 0);
        aH = __builtin_amdgcn_mfma_f32_16x16x32_bf16(Areg[c + 4], bf[c + 4], aH, 0, 0, 0);
      }
      size_t base = ((size_t)b * S + 16 * m + 4 * q) * 1024 + 16 * n + r;
#pragma unroll
      for (int i = 0; i < 4; ++i)
        out[base + (size_t)i * 1024] = aL[i] + aH[i] + boC;
    };

    __syncthreads();                      // matches scan's initial barrier
    for (int t = 0; t < S; ++t) {
      const int k = t - LAG;
      if (k >= 0 && (k & 15) == 0) loadA(k >> 4);  // A first (oldest in queue)
      const int kn = k + 1;
      if (kn >= 0) stageB(kn);            // kn <= S-LAG < S always in main loop
      if (k >= 0) {
        // retire everything except the 9 newest (B(k+1) 8 + bo 1):
        // A-loads (if any), B(k), bo(k), prev stores are all older -> done.
        asm volatile("s_waitcnt vmcnt(9)" ::: "memory");
        consume(k);
      }
      float tmp = boC; boC = boN; boN = tmp;
      BARRIER_LGKM();
    }
    // drain: tiles S-LAG .. S-1, barrier-free (scan waves exited)
    for (int k = S - LAG; k < S; ++k) {
      if ((k & 15) == 0) loadA(k >> 4);
      const int kn = k + 1;
      if (kn < S) stageB(kn);
      asm volatile("s_waitcnt vmcnt(0)" ::: "memory");
      consume(k);
      float tmp = boC; boC = boN; boN = tmp;
    }
  }
}

// ---------------------------------------------------------------- launch
extern "C" void kernel_launch(void* const* d_in, const int* in_sizes, int n_in,
                              void* d_out, int out_size, void* d_ws,
                              size_t ws_size, hipStream_t stream) {
  const float* x       = (const float*)d_in[0];  // [8,4096,1024]
  const float* W_in    = (const float*)d_in[1];  // [1024,256]
  const float* b_in    = (const float*)d_in[2];  // [256]
  const float* W_state = (const float*)d_in[3];  // [256,256]
  const float* b_state = (const float*)d_in[4];  // [256]
  const float* W_out   = (const float*)d_in[5];  // [256,1024]
  const float* b_out   = (const float*)d_in[6];  // [1024]
  float* out = (float*)d_out;                    // [8,4096,1024]

  const int B = 8, S = 4096, H = 1024, D = 256;
  const int M = B * S;  // 32768

  char* ws = (char*)d_ws;
  float*  inp    = (float*)(ws + 0);            // 32 MB  [M,D] f32
  __bf16* states = (__bf16*)(ws + 33554432);    // 16 MB  [M,D] bf16
  __bf16* xb     = (__bf16*)(ws + 50331648);    // 64 MB  [M,H] bf16
  __bf16* WinT   = (__bf16*)(ws + 117440512);   // 0.5 MB [D,H] bf16  (W_in^T)
  __bf16* WoutT  = (__bf16*)(ws + 117964800);   // 0.5 MB [H,D] bf16  (W_out^T)

  // conversions
  cvt_f32_bf16_x4<<<(M * H / 4 + 255) / 256, 256, 0, stream>>>(x, xb, M * H / 4);
  transpose_cvt<<<(H * D + 255) / 256, 256, 0, stream>>>(W_in, WinT, H, D);
  transpose_cvt<<<(D * H + 255) / 256, 256, 0, stream>>>(W_out, WoutT, D, H);

  // phase 1: inp = x @ W_in + b_in   (M=32768, N=256, K=1024) -> 512 blocks
  gemm_tile<<<(M / 128) * (D / 128), 256, 0, stream>>>(xb, WinT, b_in, inp, M, D, H);

  // phase 2+3 fused: scan + zero-VGPR LDS streamers, 768 thr/block
  scan_fused<<<B, 768, 0, stream>>>(inp, W_state, b_state, WoutT, b_out,
                                    states, out, S);
}

// Round 8
// 2105.690 us; speedup vs baseline: 4.2264x; 1.7820x over previous
//
#include <hip/hip_runtime.h>
#include <stdint.h>

// SSMTrack: B=8, S=4096, H=1024, D=256
//   inp = x @ W_in + b_in                    (tiled bf16 MFMA GEMM)
//   s_t = tanh(inp_t + s_{t-1} @ W_state + b_state)   (MFMA f16 scan, 16 waves/batch)
//   out = states @ W_out + b_out             (tiled bf16 MFMA GEMM)

typedef float v4f __attribute__((ext_vector_type(4)));
typedef __bf16 bf16x4 __attribute__((ext_vector_type(4)));
typedef __bf16 bf16x8 __attribute__((ext_vector_type(8)));
typedef _Float16 h8 __attribute__((ext_vector_type(8)));

#define BARRIER_LGKM() asm volatile("s_waitcnt lgkmcnt(0)\n\ts_barrier" ::: "memory")

#define GLOAD_LDS16(g, l)                                                    \
  __builtin_amdgcn_global_load_lds(                                          \
      (const __attribute__((address_space(1))) void*)(g),                    \
      (__attribute__((address_space(3))) void*)(l), 16, 0, 0)

// ---------------------------------------------------------------- conversions
__global__ void cvt_f32_bf16_x4(const float* __restrict__ in,
                                __bf16* __restrict__ out, int n4) {
  int i = blockIdx.x * blockDim.x + threadIdx.x;
  if (i >= n4) return;
  v4f v = ((const v4f*)in)[i];
  bf16x4 o;
  o.x = (__bf16)v.x; o.y = (__bf16)v.y; o.z = (__bf16)v.z; o.w = (__bf16)v.w;
  ((bf16x4*)out)[i] = o;
}

// in: [K,N] f32 row-major  ->  out: [N,K] bf16 row-major (i.e. B^T)
__global__ void transpose_cvt(const float* __restrict__ in,
                              __bf16* __restrict__ out, int K, int N) {
  int i = blockIdx.x * blockDim.x + threadIdx.x;
  if (i >= K * N) return;
  int k = i / N;
  int n = i - k * N;
  out[(size_t)n * K + k] = (__bf16)in[i];
}

// ---------------------------------------------------------------- GEMM (bf16)
// C[M,N](f32) = A[M,K](bf16 rm) * B + bias, with Bt[N,K] = B^T (bf16 rm).
// 128x128 block tile, BK=32, 4 waves (2x2), 4x4 fragments of 16x16x32 MFMA.
// Double-buffered LDS via global_load_lds (16B), one barrier per K-step.
__global__ __launch_bounds__(256) void gemm_tile(
    const __bf16* __restrict__ A,    // [M,K]
    const __bf16* __restrict__ Bt,   // [N,K]
    const float* __restrict__ bias,  // [N]
    float* __restrict__ C,           // [M,N]
    int M, int N, int K) {
  const int tid = threadIdx.x;
  const int lane = tid & 63;
  const int w = tid >> 6;          // wave 0..3
  const int wr = w >> 1, wc = w & 1;
  const int r = lane & 15, q = lane >> 4;

  const int nbn = N >> 7;
  const int mb = blockIdx.x / nbn;
  const int nb = blockIdx.x - mb * nbn;
  const int m0 = mb << 7, n0 = nb << 7;

  __shared__ __align__(16) char lds[2][16384];  // [buf][A 8K | B 8K]

  const __bf16* gA[2];
  const __bf16* gB[2];
  int loff[2];
#pragma unroll
  for (int j = 0; j < 2; ++j) {
    int o = (w * 2 + j) * 1024 + lane * 16;
    int row = o >> 6;
    int s = (o >> 4) & 3;
    int ss = s ^ ((row >> 1) & 3);
    gA[j] = A + (size_t)(m0 + row) * K + ss * 8;
    gB[j] = Bt + (size_t)(n0 + row) * K + ss * 8;
    loff[j] = (w * 2 + j) * 1024;
  }

  const int slot = (q ^ ((r >> 1) & 3)) * 16;
  int aoff[4], boff[4];
#pragma unroll
  for (int i = 0; i < 4; ++i) {
    aoff[i] = (wr * 64 + i * 16 + r) * 64 + slot;
    boff[i] = 8192 + (wc * 64 + i * 16 + r) * 64 + slot;
  }

  v4f acc[4][4];
#pragma unroll
  for (int mi = 0; mi < 4; ++mi)
#pragma unroll
    for (int ni = 0; ni < 4; ++ni) acc[mi][ni] = (v4f){0.f, 0.f, 0.f, 0.f};

  const int NK = K >> 5;
#pragma unroll
  for (int j = 0; j < 2; ++j) {
    GLOAD_LDS16(gA[j], lds[0] + loff[j]);
    GLOAD_LDS16(gB[j], lds[0] + 8192 + loff[j]);
  }

  for (int kt = 0; kt < NK; ++kt) {
    __syncthreads();
    if (kt + 1 < NK) {
      const int bb = (kt + 1) & 1;
      const int ke = (kt + 1) * 32;
#pragma unroll
      for (int j = 0; j < 2; ++j) {
        GLOAD_LDS16(gA[j] + ke, lds[bb] + loff[j]);
        GLOAD_LDS16(gB[j] + ke, lds[bb] + 8192 + loff[j]);
      }
    }
    const char* Lb = lds[kt & 1];
    bf16x8 af[4], bf[4];
#pragma unroll
    for (int i = 0; i < 4; ++i) af[i] = *(const bf16x8*)(Lb + aoff[i]);
#pragma unroll
    for (int i = 0; i < 4; ++i) bf[i] = *(const bf16x8*)(Lb + boff[i]);
#pragma unroll
    for (int mi = 0; mi < 4; ++mi)
#pragma unroll
      for (int ni = 0; ni < 4; ++ni)
        acc[mi][ni] = __builtin_amdgcn_mfma_f32_16x16x32_bf16(
            af[mi], bf[ni], acc[mi][ni], 0, 0, 0);
  }

  float bv[4];
#pragma unroll
  for (int ni = 0; ni < 4; ++ni) bv[ni] = bias[n0 + wc * 64 + ni * 16 + r];
#pragma unroll
  for (int mi = 0; mi < 4; ++mi) {
    int rowb = m0 + wr * 64 + mi * 16 + q * 4;
#pragma unroll
    for (int ni = 0; ni < 4; ++ni) {
      int col = n0 + wc * 64 + ni * 16 + r;
      float* cp = C + (size_t)rowb * N + col;
#pragma unroll
      for (int i = 0; i < 4; ++i) cp[(size_t)i * N] = acc[mi][ni][i] + bv[ni];
    }
  }
}

// ---------------------------------------------------------------- scan (MFMA)
// R8: 1024 threads = 16 waves = 4 waves/SIMD. History: MFMA-pipe busy/step
// is invariant at ~507 cy (128 MFMAs/block-step is structural); R3's move
// 1->2 waves/SIMD cut step 1269->1066 by hiding latency with TLP. The
// remaining ~450 cy of bubbles (ds_read ~120, chain tail, tanh, barrier
// resync) should shrink further with 4 chains per SIMD. Per-wave DS cost is
// FIXED at 8 broadcast ds_read_b128 (K=256 / 32-per-mfma, q-indexed), so
// 16 waves double DS issue (128 reads/step) on a pipe that overlaps MFMA.
// Wave w owns ONE 16-col tile (cols 16w..16w+15): W-frags = 32 VGPR, 8
// MFMAs as TWO depth-4 chains (accE even c, accO odd c; 1 extra add).
// Writers are q==0 lanes (col = 16w + r). All 16 A-rows alias the state
// vector (4-address broadcast LDS read). Single lgkm barrier per step.
__global__ __launch_bounds__(1024) void scan_mfma(
    const float* __restrict__ inp,      // [B*S, 256] f32
    const float* __restrict__ Wst,      // [256, 256] f32
    const float* __restrict__ b_state,  // [256] f32
    __bf16* __restrict__ states,        // [B*S, 256] bf16 (out)
    int S) {
  const int tid = threadIdx.x;
  const int l = tid & 63;
  const int q = l >> 4;
  const int r = l & 15;
  const int w = tid >> 6;             // wave 0..15
  const int b = blockIdx.x;

  __shared__ __align__(16) _Float16 sbuf[2][256];

  // B-fragments for tile w: lane holds B[k][col], col = 16w + r,
  // k = 32c + 8q + i. One-time f32->f16 convert. 32 VGPRs.
  h8 bw[8];
#pragma unroll
  for (int c = 0; c < 8; ++c) {
#pragma unroll
    for (int i = 0; i < 8; ++i)
      bw[c][i] = (_Float16)Wst[(size_t)(32 * c + 8 * q + i) * 256 + 16 * w + r];
  }

  const int col = 16 * w + r;          // this lane's column (writer iff q==0)
  const float bst = b_state[col];
  const float* inpb = inp + (size_t)b * S * 256;
  __bf16* stb = states + (size_t)b * S * 256;

  if (tid < 256) sbuf[0][tid] = (_Float16)0.f;  // state0 = 0
  float u_cur = inpb[col];          // u for t=0
  float u_nxt = inpb[256 + col];    // u for t=1
  __syncthreads();

  int cur = 0;
  for (int t = 0; t < S; ++t) {
    // prefetch u(t+2); ~500cy global latency hides under 2 steps
    float u_n2 = 0.f;
    if (t + 2 < S) u_n2 = inpb[(size_t)(t + 2) * 256 + col];

    // A-fragments: addr = 64c + 16q bytes -> 4 distinct addresses,
    // broadcast over 16-lane groups; all 16 A-rows = state.
    const h8* sp = (const h8*)sbuf[cur];
    h8 af[8];
#pragma unroll
    for (int c = 0; c < 8; ++c) af[c] = sp[4 * c + q];

    // two independent chains of depth 4
    v4f accE = {0.f, 0.f, 0.f, 0.f};
    v4f accO = accE;
#pragma unroll
    for (int c = 0; c < 4; ++c) {
      accE = __builtin_amdgcn_mfma_f32_16x16x32_f16(af[2 * c],     bw[2 * c],     accE, 0, 0, 0);
      accO = __builtin_amdgcn_mfma_f32_16x16x32_f16(af[2 * c + 1], bw[2 * c + 1], accO, 0, 0, 0);
    }
    // all C rows identical (A rows aliased) -> elem 0 valid for every lane
    float x = accE[0] + accO[0] + u_cur + bst;

    // tanh(x) = 1 - 2/(exp2(2*log2e*x)+1)
    float e = exp2f(2.885390082f * x);
    float sn = 1.f - 2.f * __builtin_amdgcn_rcpf(e + 1.f);

    cur ^= 1;
    if (q == 0) {
      sbuf[cur][col] = (_Float16)sn;            // ds_write_b16
      stb[(size_t)t * 256 + col] = (__bf16)sn;  // fire-and-forget store
    }
    u_cur = u_nxt;
    u_nxt = u_n2;
    BARRIER_LGKM();
  }
}

// ---------------------------------------------------------------- launch
extern "C" void kernel_launch(void* const* d_in, const int* in_sizes, int n_in,
                              void* d_out, int out_size, void* d_ws,
                              size_t ws_size, hipStream_t stream) {
  const float* x       = (const float*)d_in[0];  // [8,4096,1024]
  const float* W_in    = (const float*)d_in[1];  // [1024,256]
  const float* b_in    = (const float*)d_in[2];  // [256]
  const float* W_state = (const float*)d_in[3];  // [256,256]
  const float* b_state = (const float*)d_in[4];  // [256]
  const float* W_out   = (const float*)d_in[5];  // [256,1024]
  const float* b_out   = (const float*)d_in[6];  // [1024]
  float* out = (float*)d_out;                    // [8,4096,1024]

  const int B = 8, S = 4096, H = 1024, D = 256;
  const int M = B * S;  // 32768

  char* ws = (char*)d_ws;
  float*  inp    = (float*)(ws + 0);            // 32 MB  [M,D] f32
  __bf16* states = (__bf16*)(ws + 33554432);    // 16 MB  [M,D] bf16
  __bf16* xb     = (__bf16*)(ws + 50331648);    // 64 MB  [M,H] bf16
  __bf16* WinT   = (__bf16*)(ws + 117440512);   // 0.5 MB [D,H] bf16  (W_in^T)
  __bf16* WoutT  = (__bf16*)(ws + 117964800);   // 0.5 MB [H,D] bf16  (W_out^T)

  // conversions
  cvt_f32_bf16_x4<<<(M * H / 4 + 255) / 256, 256, 0, stream>>>(x, xb, M * H / 4);
  transpose_cvt<<<(H * D + 255) / 256, 256, 0, stream>>>(W_in, WinT, H, D);
  transpose_cvt<<<(D * H + 255) / 256, 256, 0, stream>>>(W_out, WoutT, D, H);

  // phase 1: inp = x @ W_in + b_in   (M=32768, N=256, K=1024) -> 512 blocks
  gemm_tile<<<(M / 128) * (D / 128), 256, 0, stream>>>(xb, WinT, b_in, inp, M, D, H);

  // phase 2: sequential scan, one block (16 waves) per batch
  scan_mfma<<<B, 1024, 0, stream>>>(inp, W_state, b_state, states, S);

  // phase 3: out = states @ W_out + b_out  (M=32768, N=1024, K=256) -> 2048 blocks
  gemm_tile<<<(M / 128) * (H / 128), 256, 0, stream>>>(states, WoutT, b_out, out, M, H, D);
}